// Round 1
// baseline (483.801 us; speedup 1.0000x reference)
//
#include <hip/hip_runtime.h>
#include <math.h>

// Problem constants (static per reference)
#define B_    256
#define N_    400
#define D_    256
#define E_    3276800        // B*N*DEG
#define NT_   102400         // B*N
#define K_    200            // ceil(0.5*N)
#define NKC_  200            // N-K

// Output flat offsets (float32 elements, in return order)
#define O_FDIS 0
#define O_FCOM 13107200      // + B*K*D
#define O_PERM 26214400      // + B*NKC*D
#define O_PCOM 26265600      // + B*K
#define O_SOFT 26316800      // + B*NKC
#define O_EDIS 26419200      // + NT
#define O_ECOM 29696000      // + E

#define NEG_INF (-3.402823466e38f)

__global__ __launch_bounds__(256) void k_init(int* deg_out, int* deg_in, float* score) {
    int i = blockIdx.x * 256 + threadIdx.x;
    if (i < NT_) { deg_out[i] = 0; deg_in[i] = 0; score[i] = 0.0f; }
}

__global__ __launch_bounds__(256) void k_deg(const int* __restrict__ src, const int* __restrict__ dst,
                                             int* deg_out, int* deg_in) {
    int e = blockIdx.x * 256 + threadIdx.x;
    if (e < E_) {
        atomicAdd(&deg_out[src[e]], 1);
        atomicAdd(&deg_in[dst[e]], 1);
    }
}

// h[v] = dot(feature[v], W) * max(deg_out,1)^-1/2   — one wave (64 lanes) per row
__global__ __launch_bounds__(256) void k_h(const float* __restrict__ feat, const float* __restrict__ W,
                                           const int* __restrict__ deg_out, float* __restrict__ h) {
    int gw   = (blockIdx.x * 256 + threadIdx.x) >> 6;
    int lane = threadIdx.x & 63;
    if (gw >= NT_) return;
    float4 a = ((const float4*)(feat + (size_t)gw * D_))[lane];
    float4 w = ((const float4*)W)[lane];
    float d = a.x * w.x + a.y * w.y + a.z * w.z + a.w * w.w;
    #pragma unroll
    for (int off = 32; off > 0; off >>= 1) d += __shfl_down(d, off, 64);
    if (lane == 0) {
        float dg = fmaxf((float)deg_out[gw], 1.0f);
        h[gw] = d * (1.0f / sqrtf(dg));
    }
}

__global__ __launch_bounds__(256) void k_agg(const int* __restrict__ src, const int* __restrict__ dst,
                                             const float* __restrict__ h, float* score) {
    int e = blockIdx.x * 256 + threadIdx.x;
    if (e < E_) atomicAdd(&score[dst[e]], h[src[e]]);
}

__global__ __launch_bounds__(256) void k_fin(const int* __restrict__ deg_in, const float* __restrict__ bp,
                                             float* __restrict__ score) {
    int i = blockIdx.x * 256 + threadIdx.x;
    if (i < NT_) {
        float dg = fmaxf((float)deg_in[i], 1.0f);
        score[i] = score[i] * (1.0f / sqrtf(dg)) + bp[0];
    }
}

// Per-graph top-k via 512-wide bitonic sort: key = (score desc, idx asc) matches
// jax.lax.top_k tie-breaking (lower index first). Then LDS prefix scan for the
// complement (unselected ids ascending = stable argsort of the 0/1 mask).
__global__ __launch_bounds__(256) void k_topk(const float* __restrict__ score, float* __restrict__ out,
                                              int* __restrict__ perm_i, int* __restrict__ pcom_i,
                                              int* __restrict__ sel) {
    __shared__ float skey[512];
    __shared__ int   sidx[512];
    __shared__ int   smask[N_];
    __shared__ int   nscan[512];
    const int g = blockIdx.x;
    const int tid = threadIdx.x;
    const float* s = score + g * N_;
    for (int t = tid; t < 512; t += 256) {
        skey[t] = (t < N_) ? s[t] : NEG_INF;
        sidx[t] = t;
    }
    __syncthreads();
    for (int k = 2; k <= 512; k <<= 1) {
        for (int j = k >> 1; j > 0; j >>= 1) {
            for (int t = tid; t < 512; t += 256) {
                int p = t ^ j;
                if (p > t) {
                    float ka = skey[t], kb = skey[p];
                    int ia = sidx[t], ib = sidx[p];
                    bool gt_ab = (ka > kb) || (ka == kb && ia < ib);   // a ranks before b
                    bool desc = ((t & k) == 0);
                    if (desc ? !gt_ab : gt_ab) {
                        skey[t] = kb; skey[p] = ka;
                        sidx[t] = ib; sidx[p] = ia;
                    }
                }
            }
            __syncthreads();
        }
    }
    for (int t = tid; t < N_; t += 256) smask[t] = 0;
    __syncthreads();
    if (tid < K_) {
        int id = sidx[tid];
        smask[id] = 1;
        int gi = g * N_ + id;
        perm_i[g * K_ + tid] = gi;
        out[O_PERM + g * K_ + tid] = (float)gi;
        sel[gi] = 1;
    }
    __syncthreads();
    for (int t = tid; t < 512; t += 256) nscan[t] = (t < N_) ? (1 - smask[t]) : 0;
    __syncthreads();
    // inclusive Hillis–Steele scan over 512 entries, 2 per thread
    for (int off = 1; off < 512; off <<= 1) {
        int t1 = tid, t2 = tid + 256;
        int v1 = (t1 >= off) ? nscan[t1 - off] : 0;
        int v2 = (t2 >= off) ? nscan[t2 - off] : 0;
        __syncthreads();
        nscan[t1] += v1; nscan[t2] += v2;
        __syncthreads();
    }
    for (int t = tid; t < N_; t += 256) {
        if (!smask[t]) {
            int pos = nscan[t] - 1;           // exclusive rank among unselected
            int gi = g * N_ + t;
            pcom_i[g * NKC_ + pos] = gi;
            out[O_PCOM + g * NKC_ + pos] = (float)gi;
            sel[gi] = 0;
        }
    }
}

// Global softmax over all NT nodes: per-block (max, sumexp) pairs, online combine.
__global__ __launch_bounds__(256) void k_soft_part(const float* __restrict__ score, float* pm, float* ps) {
    __shared__ float red[256];
    int b = blockIdx.x, tid = threadIdx.x;
    const float* s = score + b * N_;
    float m = NEG_INF;
    for (int i = tid; i < N_; i += 256) m = fmaxf(m, s[i]);
    red[tid] = m; __syncthreads();
    for (int o = 128; o > 0; o >>= 1) { if (tid < o) red[tid] = fmaxf(red[tid], red[tid + o]); __syncthreads(); }
    float M = red[0]; __syncthreads();
    float acc = 0.0f;
    for (int i = tid; i < N_; i += 256) acc += expf(s[i] - M);
    red[tid] = acc; __syncthreads();
    for (int o = 128; o > 0; o >>= 1) { if (tid < o) red[tid] += red[tid + o]; __syncthreads(); }
    if (tid == 0) { pm[b] = M; ps[b] = red[0]; }
}

__global__ __launch_bounds__(256) void k_soft_comb(const float* pm, const float* ps, float* red2) {
    __shared__ float rm[256], rs[256];
    int tid = threadIdx.x;
    float m = pm[tid];
    rm[tid] = m; __syncthreads();
    for (int o = 128; o > 0; o >>= 1) { if (tid < o) rm[tid] = fmaxf(rm[tid], rm[tid + o]); __syncthreads(); }
    float M = rm[0]; __syncthreads();
    rs[tid] = ps[tid] * expf(m - M); __syncthreads();
    for (int o = 128; o > 0; o >>= 1) { if (tid < o) rs[tid] += rs[tid + o]; __syncthreads(); }
    if (tid == 0) { red2[0] = M; red2[1] = rs[0]; }
}

__global__ __launch_bounds__(256) void k_soft_write(const float* __restrict__ score, const float* __restrict__ red2,
                                                    float* __restrict__ out) {
    int i = blockIdx.x * 256 + threadIdx.x;
    if (i < NT_) out[O_SOFT + i] = expf(score[i] - red2[0]) / red2[1];
}

// Gated gathers: one wave per output row; dis rows [0,B*K), com rows after.
__global__ __launch_bounds__(256) void k_gather(const float* __restrict__ feat, const float* __restrict__ score,
                                                const int* __restrict__ perm_i, const int* __restrict__ pcom_i,
                                                float* __restrict__ out) {
    int row  = (blockIdx.x * 256 + threadIdx.x) >> 6;
    int lane = threadIdx.x & 63;
    if (row >= B_ * N_) return;
    int node; size_t obase;
    if (row < B_ * K_) { node = perm_i[row];            obase = (size_t)O_FDIS + (size_t)row * D_; }
    else { int r = row - B_ * K_; node = pcom_i[r];     obase = (size_t)O_FCOM + (size_t)r   * D_; }
    float t = tanhf(score[node]);
    float4 v = ((const float4*)(feat + (size_t)node * D_))[lane];
    v.x *= t; v.y *= t; v.z *= t; v.w *= t;
    ((float4*)(out + obase))[lane] = v;
}

__global__ __launch_bounds__(256) void k_mask(const int* __restrict__ src, const int* __restrict__ dst,
                                              const int* __restrict__ sel, float* __restrict__ out) {
    int e = blockIdx.x * 256 + threadIdx.x;
    if (e < E_) {
        int a = sel[src[e]];
        int b = sel[dst[e]];
        out[O_EDIS + e] = (a & b) ? 1.0f : 0.0f;
        out[O_ECOM + e] = ((a | b) == 0) ? 1.0f : 0.0f;
    }
}

extern "C" void kernel_launch(void* const* d_in, const int* in_sizes, int n_in,
                              void* d_out, int out_size, void* d_ws, size_t ws_size,
                              hipStream_t stream) {
    const float* feat = (const float*)d_in[0];
    const float* W    = (const float*)d_in[1];
    const float* bp   = (const float*)d_in[2];
    const int*   src  = (const int*)d_in[3];
    const int*   dst  = (const int*)d_in[4];
    float* out = (float*)d_out;

    char* ws = (char*)d_ws;
    int*   deg_out = (int*)  (ws + 0);
    int*   deg_in  = (int*)  (ws + 409600);
    float* h       = (float*)(ws + 819200);
    float* score   = (float*)(ws + 1228800);
    int*   sel     = (int*)  (ws + 1638400);
    int*   perm_i  = (int*)  (ws + 2048000);
    int*   pcom_i  = (int*)  (ws + 2252800);
    float* pm      = (float*)(ws + 2457600);
    float* ps      = (float*)(ws + 2458624);
    float* red2    = (float*)(ws + 2459648);

    k_init      <<<(NT_ + 255) / 256, 256, 0, stream>>>(deg_out, deg_in, score);
    k_deg       <<<(E_  + 255) / 256, 256, 0, stream>>>(src, dst, deg_out, deg_in);
    k_h         <<<(NT_ * 64) / 256,  256, 0, stream>>>(feat, W, deg_out, h);
    k_agg       <<<(E_  + 255) / 256, 256, 0, stream>>>(src, dst, h, score);
    k_fin       <<<(NT_ + 255) / 256, 256, 0, stream>>>(deg_in, bp, score);
    k_topk      <<<B_,                256, 0, stream>>>(score, out, perm_i, pcom_i, sel);
    k_soft_part <<<B_,                256, 0, stream>>>(score, pm, ps);
    k_soft_comb <<<1,                 256, 0, stream>>>(pm, ps, red2);
    k_soft_write<<<(NT_ + 255) / 256, 256, 0, stream>>>(score, red2, out);
    k_gather    <<<(B_ * N_ * 64) / 256, 256, 0, stream>>>(feat, score, perm_i, pcom_i, out);
    k_mask      <<<(E_  + 255) / 256, 256, 0, stream>>>(src, dst, sel, out);
}

// Round 2
// 339.381 us; speedup vs baseline: 1.4255x; 1.4255x over previous
//
#include <hip/hip_runtime.h>
#include <math.h>

// Problem constants (static per reference)
#define B_    256
#define N_    400
#define D_    256
#define DEG_  32
#define EPG_  12800          // N*DEG edges per graph (block-diagonal, contiguous)
#define E_    3276800        // B*EPG
#define NT_   102400         // B*N
#define K_    200            // ceil(0.5*N)
#define NKC_  200            // N-K

// Output flat offsets (float32 elements, in return order)
#define O_FDIS 0
#define O_FCOM 13107200      // + B*K*D
#define O_PERM 26214400      // + B*NKC*D
#define O_PCOM 26265600      // + B*K
#define O_SOFT 26316800      // + B*NKC
#define O_EDIS 26419200      // + NT
#define O_ECOM 29696000      // + E

#define NEG_INF (-3.402823466e38f)

// Fused per-graph score pipeline: degrees + (X·W)*norm_out + edge scatter-sum
// + norm_in + bias. One block per graph; ALL scatters hit LDS, zero global
// atomics. Edges are read from HBM exactly once (local ids cached as u16).
__global__ __launch_bounds__(256) void k_score(const float* __restrict__ feat,
                                               const float* __restrict__ W,
                                               const float* __restrict__ bp,
                                               const int* __restrict__ src,
                                               const int* __restrict__ dst,
                                               float* __restrict__ score) {
    __shared__ unsigned short lsrc[EPG_];
    __shared__ unsigned short ldst[EPG_];
    __shared__ float hloc[N_];
    __shared__ float scl[N_];
    __shared__ float wsh[D_];
    __shared__ int   dego[N_];
    __shared__ int   degi[N_];

    const int g = blockIdx.x, tid = threadIdx.x;
    const int ebase = g * EPG_;
    const int nbase = g * N_;

    for (int t = tid; t < N_; t += 256) { dego[t] = 0; degi[t] = 0; scl[t] = 0.0f; }
    for (int t = tid; t < D_; t += 256) wsh[t] = W[t];
    __syncthreads();

    // Pass A: edge load (coalesced, once) + LDS degree histograms
    for (int i = tid; i < EPG_; i += 256) {
        int s = src[ebase + i] - nbase;
        int d = dst[ebase + i] - nbase;
        lsrc[i] = (unsigned short)s;
        ldst[i] = (unsigned short)d;
        atomicAdd(&dego[s], 1);
        atomicAdd(&degi[d], 1);
    }
    __syncthreads();

    // Pass B: h[r] = dot(feat[r], W) * max(deg_out,1)^-1/2.
    // Wave-per-row, 4 rows in flight per wave for memory-level parallelism.
    const int wave = tid >> 6, lane = tid & 63;
    const float4 w4 = ((const float4*)wsh)[lane];
    for (int r = wave; r < N_; r += 16) {   // N_=400 = 16*25, exact
        float4 a0 = ((const float4*)(feat + (size_t)(nbase + r     ) * D_))[lane];
        float4 a1 = ((const float4*)(feat + (size_t)(nbase + r +  4) * D_))[lane];
        float4 a2 = ((const float4*)(feat + (size_t)(nbase + r +  8) * D_))[lane];
        float4 a3 = ((const float4*)(feat + (size_t)(nbase + r + 12) * D_))[lane];
        float d0 = a0.x*w4.x + a0.y*w4.y + a0.z*w4.z + a0.w*w4.w;
        float d1 = a1.x*w4.x + a1.y*w4.y + a1.z*w4.z + a1.w*w4.w;
        float d2 = a2.x*w4.x + a2.y*w4.y + a2.z*w4.z + a2.w*w4.w;
        float d3 = a3.x*w4.x + a3.y*w4.y + a3.z*w4.z + a3.w*w4.w;
        #pragma unroll
        for (int off = 32; off > 0; off >>= 1) {
            d0 += __shfl_down(d0, off, 64);
            d1 += __shfl_down(d1, off, 64);
            d2 += __shfl_down(d2, off, 64);
            d3 += __shfl_down(d3, off, 64);
        }
        if (lane == 0) {
            hloc[r     ] = d0 * (1.0f / sqrtf(fmaxf((float)dego[r     ], 1.0f)));
            hloc[r +  4] = d1 * (1.0f / sqrtf(fmaxf((float)dego[r +  4], 1.0f)));
            hloc[r +  8] = d2 * (1.0f / sqrtf(fmaxf((float)dego[r +  8], 1.0f)));
            hloc[r + 12] = d3 * (1.0f / sqrtf(fmaxf((float)dego[r + 12], 1.0f)));
        }
    }
    __syncthreads();

    // Pass C: scatter-sum via LDS float atomics (edges from LDS, no HBM)
    for (int i = tid; i < EPG_; i += 256) {
        atomicAdd(&scl[ldst[i]], hloc[lsrc[i]]);
    }
    __syncthreads();

    // Pass D: finalize + write score
    const float bb = bp[0];
    for (int t = tid; t < N_; t += 256) {
        score[nbase + t] = scl[t] * (1.0f / sqrtf(fmaxf((float)degi[t], 1.0f))) + bb;
    }
}

// Per-graph top-k via 512-wide bitonic sort: key = (score desc, idx asc) matches
// jax.lax.top_k tie-breaking (lower index first). Then LDS prefix scan for the
// complement (unselected ids ascending = stable argsort of the 0/1 mask).
__global__ __launch_bounds__(256) void k_topk(const float* __restrict__ score, float* __restrict__ out,
                                              int* __restrict__ perm_i, int* __restrict__ pcom_i,
                                              int* __restrict__ sel) {
    __shared__ float skey[512];
    __shared__ int   sidx[512];
    __shared__ int   smask[N_];
    __shared__ int   nscan[512];
    const int g = blockIdx.x;
    const int tid = threadIdx.x;
    const float* s = score + g * N_;
    for (int t = tid; t < 512; t += 256) {
        skey[t] = (t < N_) ? s[t] : NEG_INF;
        sidx[t] = t;
    }
    __syncthreads();
    for (int k = 2; k <= 512; k <<= 1) {
        for (int j = k >> 1; j > 0; j >>= 1) {
            for (int t = tid; t < 512; t += 256) {
                int p = t ^ j;
                if (p > t) {
                    float ka = skey[t], kb = skey[p];
                    int ia = sidx[t], ib = sidx[p];
                    bool gt_ab = (ka > kb) || (ka == kb && ia < ib);   // a ranks before b
                    bool desc = ((t & k) == 0);
                    if (desc ? !gt_ab : gt_ab) {
                        skey[t] = kb; skey[p] = ka;
                        sidx[t] = ib; sidx[p] = ia;
                    }
                }
            }
            __syncthreads();
        }
    }
    for (int t = tid; t < N_; t += 256) smask[t] = 0;
    __syncthreads();
    if (tid < K_) {
        int id = sidx[tid];
        smask[id] = 1;
        int gi = g * N_ + id;
        perm_i[g * K_ + tid] = gi;
        out[O_PERM + g * K_ + tid] = (float)gi;
        sel[gi] = 1;
    }
    __syncthreads();
    for (int t = tid; t < 512; t += 256) nscan[t] = (t < N_) ? (1 - smask[t]) : 0;
    __syncthreads();
    // inclusive Hillis–Steele scan over 512 entries, 2 per thread
    for (int off = 1; off < 512; off <<= 1) {
        int t1 = tid, t2 = tid + 256;
        int v1 = (t1 >= off) ? nscan[t1 - off] : 0;
        int v2 = (t2 >= off) ? nscan[t2 - off] : 0;
        __syncthreads();
        nscan[t1] += v1; nscan[t2] += v2;
        __syncthreads();
    }
    for (int t = tid; t < N_; t += 256) {
        if (!smask[t]) {
            int pos = nscan[t] - 1;           // exclusive rank among unselected
            int gi = g * N_ + t;
            pcom_i[g * NKC_ + pos] = gi;
            out[O_PCOM + g * NKC_ + pos] = (float)gi;
            sel[gi] = 0;
        }
    }
}

// Global softmax over all NT nodes: per-block (max, sumexp) pairs, online combine.
__global__ __launch_bounds__(256) void k_soft_part(const float* __restrict__ score, float* pm, float* ps) {
    __shared__ float red[256];
    int b = blockIdx.x, tid = threadIdx.x;
    const float* s = score + b * N_;
    float m = NEG_INF;
    for (int i = tid; i < N_; i += 256) m = fmaxf(m, s[i]);
    red[tid] = m; __syncthreads();
    for (int o = 128; o > 0; o >>= 1) { if (tid < o) red[tid] = fmaxf(red[tid], red[tid + o]); __syncthreads(); }
    float M = red[0]; __syncthreads();
    float acc = 0.0f;
    for (int i = tid; i < N_; i += 256) acc += expf(s[i] - M);
    red[tid] = acc; __syncthreads();
    for (int o = 128; o > 0; o >>= 1) { if (tid < o) red[tid] += red[tid + o]; __syncthreads(); }
    if (tid == 0) { pm[b] = M; ps[b] = red[0]; }
}

__global__ __launch_bounds__(256) void k_soft_comb(const float* pm, const float* ps, float* red2) {
    __shared__ float rm[256], rs[256];
    int tid = threadIdx.x;
    float m = pm[tid];
    rm[tid] = m; __syncthreads();
    for (int o = 128; o > 0; o >>= 1) { if (tid < o) rm[tid] = fmaxf(rm[tid], rm[tid + o]); __syncthreads(); }
    float M = rm[0]; __syncthreads();
    rs[tid] = ps[tid] * expf(m - M); __syncthreads();
    for (int o = 128; o > 0; o >>= 1) { if (tid < o) rs[tid] += rs[tid + o]; __syncthreads(); }
    if (tid == 0) { red2[0] = M; red2[1] = rs[0]; }
}

__global__ __launch_bounds__(256) void k_soft_write(const float* __restrict__ score, const float* __restrict__ red2,
                                                    float* __restrict__ out) {
    int i = blockIdx.x * 256 + threadIdx.x;
    if (i < NT_) out[O_SOFT + i] = expf(score[i] - red2[0]) / red2[1];
}

// Gated gathers: one wave per output row; dis rows [0,B*K), com rows after.
__global__ __launch_bounds__(256) void k_gather(const float* __restrict__ feat, const float* __restrict__ score,
                                                const int* __restrict__ perm_i, const int* __restrict__ pcom_i,
                                                float* __restrict__ out) {
    int row  = (blockIdx.x * 256 + threadIdx.x) >> 6;
    int lane = threadIdx.x & 63;
    if (row >= B_ * N_) return;
    int node; size_t obase;
    if (row < B_ * K_) { node = perm_i[row];            obase = (size_t)O_FDIS + (size_t)row * D_; }
    else { int r = row - B_ * K_; node = pcom_i[r];     obase = (size_t)O_FCOM + (size_t)r   * D_; }
    float t = tanhf(score[node]);
    float4 v = ((const float4*)(feat + (size_t)node * D_))[lane];
    v.x *= t; v.y *= t; v.z *= t; v.w *= t;
    ((float4*)(out + obase))[lane] = v;
}

__global__ __launch_bounds__(256) void k_mask(const int* __restrict__ src, const int* __restrict__ dst,
                                              const int* __restrict__ sel, float* __restrict__ out) {
    int e = blockIdx.x * 256 + threadIdx.x;
    if (e < E_) {
        int a = sel[src[e]];
        int b = sel[dst[e]];
        out[O_EDIS + e] = (a & b) ? 1.0f : 0.0f;
        out[O_ECOM + e] = ((a | b) == 0) ? 1.0f : 0.0f;
    }
}

extern "C" void kernel_launch(void* const* d_in, const int* in_sizes, int n_in,
                              void* d_out, int out_size, void* d_ws, size_t ws_size,
                              hipStream_t stream) {
    const float* feat = (const float*)d_in[0];
    const float* W    = (const float*)d_in[1];
    const float* bp   = (const float*)d_in[2];
    const int*   src  = (const int*)d_in[3];
    const int*   dst  = (const int*)d_in[4];
    float* out = (float*)d_out;

    char* ws = (char*)d_ws;
    float* score   = (float*)(ws + 0);
    int*   sel     = (int*)  (ws + 409600);
    int*   perm_i  = (int*)  (ws + 819200);
    int*   pcom_i  = (int*)  (ws + 1024000);
    float* pm      = (float*)(ws + 1228800);
    float* ps      = (float*)(ws + 1229824);
    float* red2    = (float*)(ws + 1230848);

    k_score     <<<B_,                256, 0, stream>>>(feat, W, bp, src, dst, score);
    k_topk      <<<B_,                256, 0, stream>>>(score, out, perm_i, pcom_i, sel);
    k_soft_part <<<B_,                256, 0, stream>>>(score, pm, ps);
    k_soft_comb <<<1,                 256, 0, stream>>>(pm, ps, red2);
    k_soft_write<<<(NT_ + 255) / 256, 256, 0, stream>>>(score, red2, out);
    k_gather    <<<(B_ * N_ * 64) / 256, 256, 0, stream>>>(feat, score, perm_i, pcom_i, out);
    k_mask      <<<(E_  + 255) / 256, 256, 0, stream>>>(src, dst, sel, out);
}

// Round 3
// 279.243 us; speedup vs baseline: 1.7325x; 1.2154x over previous
//
#include <hip/hip_runtime.h>
#include <math.h>

// Problem constants (static per reference)
#define B_    256
#define N_    400
#define D_    256
#define DEG_  32
#define EPG_  12800          // N*DEG edges per graph (block-diagonal, contiguous)
#define E_    3276800        // B*EPG
#define NT_   102400         // B*N
#define K_    200            // ceil(0.5*N)
#define NKC_  200            // N-K

// Output flat offsets (float32 elements, in return order)
#define O_FDIS 0
#define O_FCOM 13107200      // + B*K*D
#define O_PERM 26214400      // + B*NKC*D
#define O_PCOM 26265600      // + B*K
#define O_SOFT 26316800      // + B*NKC
#define O_EDIS 26419200      // + NT
#define O_ECOM 29696000      // + E

#define NEG_INF (-3.402823466e38f)

// LDS overlay: group1 (passes A-D) vs group2 (sort/scan/gather/mask phases).
struct G1 {
    float wsh[D_];     // W cached
    float hloc[N_];    // h per node
    int   dego[N_];
    int   degi[N_];
};
struct G2 {
    float skey[512];   // bitonic sort keys
    int   sidx[512];   // bitonic sort ids
    int   smask[N_];   // selected mask
    int   nscan[512];  // complement prefix scan
    int   lrow[N_];    // output row -> local node id (0..199 dis, 200..399 com)
};
union Ovl { G1 g1; G2 g2; };

// One block per graph, 1024 threads (16 waves). Entire per-graph pipeline:
// degrees -> h = (X.W)*norm_out -> LDS scatter-sum -> score -> softmax partial
// -> bitonic top-k -> complement scan -> gated gathers -> edge masks.
// Edges read from HBM exactly once (packed u16 pairs cached in LDS).
__global__ __launch_bounds__(1024) void k_mega(const float* __restrict__ feat,
                                               const float* __restrict__ W,
                                               const float* __restrict__ bp,
                                               const int* __restrict__ src,
                                               const int* __restrict__ dst,
                                               float* __restrict__ score,
                                               float* __restrict__ pm,
                                               float* __restrict__ ps,
                                               float* __restrict__ out) {
    __shared__ unsigned int lpack[EPG_];   // (dst<<16)|src local ids, 51.2 KB
    __shared__ float scl[N_];              // running score per node
    __shared__ Ovl ovl;                    // 9.3 KB overlay

    const int g = blockIdx.x, tid = threadIdx.x;
    const int ebase = g * EPG_;
    const int nbase = g * N_;
    const int wave = tid >> 6, lane = tid & 63;

    // init
    for (int t = tid; t < N_; t += 1024) { ovl.g1.dego[t] = 0; ovl.g1.degi[t] = 0; scl[t] = 0.0f; }
    if (tid < D_) ovl.g1.wsh[tid] = W[tid];
    __syncthreads();

    // Pass A: edge load (int4-vectorized, once) + LDS degree histograms
    {
        const int4* s4p = (const int4*)(src + ebase);
        const int4* d4p = (const int4*)(dst + ebase);
        for (int i = tid; i < EPG_ / 4; i += 1024) {
            int4 s4 = s4p[i];
            int4 d4 = d4p[i];
            s4.x -= nbase; s4.y -= nbase; s4.z -= nbase; s4.w -= nbase;
            d4.x -= nbase; d4.y -= nbase; d4.z -= nbase; d4.w -= nbase;
            uint4 pk;
            pk.x = (unsigned)s4.x | ((unsigned)d4.x << 16);
            pk.y = (unsigned)s4.y | ((unsigned)d4.y << 16);
            pk.z = (unsigned)s4.z | ((unsigned)d4.z << 16);
            pk.w = (unsigned)s4.w | ((unsigned)d4.w << 16);
            ((uint4*)lpack)[i] = pk;
            atomicAdd(&ovl.g1.dego[s4.x], 1);
            atomicAdd(&ovl.g1.dego[s4.y], 1);
            atomicAdd(&ovl.g1.dego[s4.z], 1);
            atomicAdd(&ovl.g1.dego[s4.w], 1);
            atomicAdd(&ovl.g1.degi[d4.x], 1);
            atomicAdd(&ovl.g1.degi[d4.y], 1);
            atomicAdd(&ovl.g1.degi[d4.z], 1);
            atomicAdd(&ovl.g1.degi[d4.w], 1);
        }
    }
    __syncthreads();

    // Pass B: h[r] = dot(feat[r], W) * max(deg_out,1)^-1/2. Wave per row,
    // 25 rows/wave, ILP-4 chunks for memory-level parallelism.
    {
        const float4 w4 = ((const float4*)ovl.g1.wsh)[lane];
        const float4* fb = (const float4*)(feat + (size_t)nbase * D_);
        #pragma unroll
        for (int c = 0; c < 6; ++c) {
            int r0 = wave + c * 64;
            float4 a0 = fb[(r0      ) * 64 + lane];
            float4 a1 = fb[(r0 + 16 ) * 64 + lane];
            float4 a2 = fb[(r0 + 32 ) * 64 + lane];
            float4 a3 = fb[(r0 + 48 ) * 64 + lane];
            float d0 = a0.x*w4.x + a0.y*w4.y + a0.z*w4.z + a0.w*w4.w;
            float d1 = a1.x*w4.x + a1.y*w4.y + a1.z*w4.z + a1.w*w4.w;
            float d2 = a2.x*w4.x + a2.y*w4.y + a2.z*w4.z + a2.w*w4.w;
            float d3 = a3.x*w4.x + a3.y*w4.y + a3.z*w4.z + a3.w*w4.w;
            #pragma unroll
            for (int off = 32; off > 0; off >>= 1) {
                d0 += __shfl_down(d0, off, 64);
                d1 += __shfl_down(d1, off, 64);
                d2 += __shfl_down(d2, off, 64);
                d3 += __shfl_down(d3, off, 64);
            }
            if (lane == 0) {
                ovl.g1.hloc[r0     ] = d0 * (1.0f / sqrtf(fmaxf((float)ovl.g1.dego[r0     ], 1.0f)));
                ovl.g1.hloc[r0 + 16] = d1 * (1.0f / sqrtf(fmaxf((float)ovl.g1.dego[r0 + 16], 1.0f)));
                ovl.g1.hloc[r0 + 32] = d2 * (1.0f / sqrtf(fmaxf((float)ovl.g1.dego[r0 + 32], 1.0f)));
                ovl.g1.hloc[r0 + 48] = d3 * (1.0f / sqrtf(fmaxf((float)ovl.g1.dego[r0 + 48], 1.0f)));
            }
        }
        {   // leftover row: wave + 384
            int r = wave + 384;
            float4 a = fb[r * 64 + lane];
            float d = a.x*w4.x + a.y*w4.y + a.z*w4.z + a.w*w4.w;
            #pragma unroll
            for (int off = 32; off > 0; off >>= 1) d += __shfl_down(d, off, 64);
            if (lane == 0)
                ovl.g1.hloc[r] = d * (1.0f / sqrtf(fmaxf((float)ovl.g1.dego[r], 1.0f)));
        }
    }
    __syncthreads();

    // Pass C: scatter-sum via LDS float atomics (edges from LDS, zero HBM)
    for (int i = tid; i < EPG_; i += 1024) {
        unsigned p = lpack[i];
        atomicAdd(&scl[p >> 16], ovl.g1.hloc[p & 0xffff]);
    }
    __syncthreads();

    // Pass D: finalize score, write to global (for global softmax write later)
    {
        const float bb = bp[0];
        for (int t = tid; t < N_; t += 1024) {
            float v = scl[t] * (1.0f / sqrtf(fmaxf((float)ovl.g1.degi[t], 1.0f))) + bb;
            scl[t] = v;
            score[nbase + t] = v;
        }
    }
    __syncthreads();
    // ---- group1 dead; group2 live from here ----

    // Sort init (tid<512) in parallel with wave-0 softmax partials (reads scl
    // only; no barriers crossed before the next __syncthreads()).
    if (tid < 512) {
        ovl.g2.skey[tid] = (tid < N_) ? scl[tid] : NEG_INF;
        ovl.g2.sidx[tid] = tid;
    }
    if (wave == 15) {   // wave 15 is idle in the tid<512 init
        float m = NEG_INF;
        for (int i = lane; i < N_; i += 64) m = fmaxf(m, scl[i]);
        #pragma unroll
        for (int o = 32; o > 0; o >>= 1) m = fmaxf(m, __shfl_xor(m, o, 64));
        float s = 0.0f;
        for (int i = lane; i < N_; i += 64) s += expf(scl[i] - m);
        #pragma unroll
        for (int o = 32; o > 0; o >>= 1) s += __shfl_xor(s, o, 64);
        if (lane == 0) { pm[g] = m; ps[g] = s; }
    }
    __syncthreads();

    // Bitonic sort, 512 wide: key = (score desc, idx asc) == jax.lax.top_k order
    for (int k = 2; k <= 512; k <<= 1) {
        for (int j = k >> 1; j > 0; j >>= 1) {
            if (tid < 512) {
                int p = tid ^ j;
                if (p > tid) {
                    float ka = ovl.g2.skey[tid], kb = ovl.g2.skey[p];
                    int ia = ovl.g2.sidx[tid], ib = ovl.g2.sidx[p];
                    bool gt_ab = (ka > kb) || (ka == kb && ia < ib);
                    bool desc = ((tid & k) == 0);
                    if (desc ? !gt_ab : gt_ab) {
                        ovl.g2.skey[tid] = kb; ovl.g2.skey[p] = ka;
                        ovl.g2.sidx[tid] = ib; ovl.g2.sidx[p] = ia;
                    }
                }
            }
            __syncthreads();
        }
    }

    // Selected set: top-K ids; write perm (as float global ids)
    for (int t = tid; t < N_; t += 1024) ovl.g2.smask[t] = 0;
    __syncthreads();
    if (tid < K_) {
        int id = ovl.g2.sidx[tid];
        ovl.g2.smask[id] = 1;
        ovl.g2.lrow[tid] = id;
        out[O_PERM + g * K_ + tid] = (float)(nbase + id);
    }
    __syncthreads();
    if (tid < 512) ovl.g2.nscan[tid] = (tid < N_) ? (1 - ovl.g2.smask[tid]) : 0;
    __syncthreads();
    // Hillis-Steele inclusive scan over 512
    for (int off = 1; off < 512; off <<= 1) {
        int v = 0;
        if (tid < 512 && tid >= off) v = ovl.g2.nscan[tid - off];
        __syncthreads();
        if (tid < 512) ovl.g2.nscan[tid] += v;
        __syncthreads();
    }
    for (int t = tid; t < N_; t += 1024) {
        if (!ovl.g2.smask[t]) {
            int pos = ovl.g2.nscan[t] - 1;
            ovl.g2.lrow[K_ + pos] = t;
            out[O_PCOM + g * NKC_ + pos] = (float)(nbase + t);
        }
    }
    __syncthreads();

    // Pass G: gated gathers. Wave per output row (0..199 dis, 200..399 com);
    // feature rows likely still in this XCD's L2 from pass B.
    {
        const float4* fb = (const float4*)(feat + (size_t)nbase * D_);
        #pragma unroll
        for (int c = 0; c < 6; ++c) {
            int j0 = wave + c * 64;
            int n0 = ovl.g2.lrow[j0     ];
            int n1 = ovl.g2.lrow[j0 + 16];
            int n2 = ovl.g2.lrow[j0 + 32];
            int n3 = ovl.g2.lrow[j0 + 48];
            float4 v0 = fb[n0 * 64 + lane];
            float4 v1 = fb[n1 * 64 + lane];
            float4 v2 = fb[n2 * 64 + lane];
            float4 v3 = fb[n3 * 64 + lane];
            float t0 = tanhf(scl[n0]), t1 = tanhf(scl[n1]);
            float t2 = tanhf(scl[n2]), t3 = tanhf(scl[n3]);
            v0.x *= t0; v0.y *= t0; v0.z *= t0; v0.w *= t0;
            v1.x *= t1; v1.y *= t1; v1.z *= t1; v1.w *= t1;
            v2.x *= t2; v2.y *= t2; v2.z *= t2; v2.w *= t2;
            v3.x *= t3; v3.y *= t3; v3.z *= t3; v3.w *= t3;
            int jj[4] = { j0, j0 + 16, j0 + 32, j0 + 48 };
            float4 vv[4] = { v0, v1, v2, v3 };
            #pragma unroll
            for (int q = 0; q < 4; ++q) {
                int j = jj[q];
                size_t obase = (j < K_)
                    ? ((size_t)O_FDIS + ((size_t)g * K_ + j) * D_)
                    : ((size_t)O_FCOM + ((size_t)g * NKC_ + (j - K_)) * D_);
                ((float4*)(out + obase))[lane] = vv[q];
            }
        }
        {   // leftover row
            int j = wave + 384;
            int n = ovl.g2.lrow[j];
            float4 v = fb[n * 64 + lane];
            float t = tanhf(scl[n]);
            v.x *= t; v.y *= t; v.z *= t; v.w *= t;
            size_t obase = (j < K_)
                ? ((size_t)O_FDIS + ((size_t)g * K_ + j) * D_)
                : ((size_t)O_FCOM + ((size_t)g * NKC_ + (j - K_)) * D_);
            ((float4*)(out + obase))[lane] = v;
        }
    }

    // Pass H: edge masks from LDS-cached edges (no HBM edge re-read)
    {
        float* odis = out + O_EDIS + ebase;
        float* ocom = out + O_ECOM + ebase;
        for (int i = tid; i < EPG_; i += 1024) {
            unsigned p = lpack[i];
            int a = ovl.g2.smask[p & 0xffff];
            int b = ovl.g2.smask[p >> 16];
            odis[i] = (a & b) ? 1.0f : 0.0f;
            ocom[i] = (a | b) ? 0.0f : 1.0f;
        }
    }
}

// Combine per-graph (max,sumexp) into global (M,S)
__global__ __launch_bounds__(256) void k_soft_comb(const float* pm, const float* ps, float* red2) {
    __shared__ float rm[256], rs[256];
    int tid = threadIdx.x;
    float m = pm[tid];
    rm[tid] = m; __syncthreads();
    for (int o = 128; o > 0; o >>= 1) { if (tid < o) rm[tid] = fmaxf(rm[tid], rm[tid + o]); __syncthreads(); }
    float M = rm[0]; __syncthreads();
    rs[tid] = ps[tid] * expf(m - M); __syncthreads();
    for (int o = 128; o > 0; o >>= 1) { if (tid < o) rs[tid] += rs[tid + o]; __syncthreads(); }
    if (tid == 0) { red2[0] = M; red2[1] = rs[0]; }
}

__global__ __launch_bounds__(256) void k_soft_write(const float* __restrict__ score, const float* __restrict__ red2,
                                                    float* __restrict__ out) {
    int i = blockIdx.x * 256 + threadIdx.x;
    if (i < NT_) out[O_SOFT + i] = expf(score[i] - red2[0]) / red2[1];
}

extern "C" void kernel_launch(void* const* d_in, const int* in_sizes, int n_in,
                              void* d_out, int out_size, void* d_ws, size_t ws_size,
                              hipStream_t stream) {
    const float* feat = (const float*)d_in[0];
    const float* W    = (const float*)d_in[1];
    const float* bp   = (const float*)d_in[2];
    const int*   src  = (const int*)d_in[3];
    const int*   dst  = (const int*)d_in[4];
    float* out = (float*)d_out;

    char* ws = (char*)d_ws;
    float* score = (float*)(ws + 0);         // NT_ floats
    float* pm    = (float*)(ws + 409600);    // B_ floats
    float* ps    = (float*)(ws + 410624);    // B_ floats
    float* red2  = (float*)(ws + 411648);    // 2 floats

    k_mega      <<<B_, 1024, 0, stream>>>(feat, W, bp, src, dst, score, pm, ps, out);
    k_soft_comb <<<1,   256, 0, stream>>>(pm, ps, red2);
    k_soft_write<<<(NT_ + 255) / 256, 256, 0, stream>>>(score, red2, out);
}

// Round 4
// 243.976 us; speedup vs baseline: 1.9830x; 1.1446x over previous
//
#include <hip/hip_runtime.h>
#include <math.h>

// Problem constants (static per reference)
#define B_    256
#define N_    400
#define D_    256
#define EPG_  12800          // N*DEG edges per graph (block-diagonal, contiguous)
#define E_    3276800        // B*EPG
#define NT_   102400         // B*N
#define K_    200            // ceil(0.5*N)
#define NKC_  200            // N-K

// Output flat offsets (float32 elements, in return order).
// NOTE: O_FDIS..O_FCOM regions are contiguous, so concatenated output row
// r in [0, B*N) lives at out + r*D  (r < B*K => dis, else com).
#define O_FDIS 0
#define O_FCOM 13107200      // + B*K*D
#define O_PERM 26214400      // + B*NKC*D
#define O_PCOM 26265600      // + B*K
#define O_SOFT 26316800      // + B*NKC
#define O_EDIS 26419200      // + NT
#define O_ECOM 29696000      // + E

#define NEG_INF (-3.402823466e38f)

// Raw dot products for ALL rows: hraw[n] = dot(feat[n], W). Wave per row,
// 4 consecutive rows per wave for MLP. Pure 100 MB stream, saturating grid.
__global__ __launch_bounds__(256) void k_h(const float* __restrict__ feat,
                                           const float* __restrict__ W,
                                           float* __restrict__ hraw) {
    const int gw   = (blockIdx.x * 256 + threadIdx.x) >> 6;
    const int lane = threadIdx.x & 63;
    const float4 w4 = ((const float4*)W)[lane];
    const int r0 = gw * 4;
    const float4* fb = (const float4*)feat;
    float4 a0 = fb[(size_t)(r0    ) * 64 + lane];
    float4 a1 = fb[(size_t)(r0 + 1) * 64 + lane];
    float4 a2 = fb[(size_t)(r0 + 2) * 64 + lane];
    float4 a3 = fb[(size_t)(r0 + 3) * 64 + lane];
    float d0 = a0.x*w4.x + a0.y*w4.y + a0.z*w4.z + a0.w*w4.w;
    float d1 = a1.x*w4.x + a1.y*w4.y + a1.z*w4.z + a1.w*w4.w;
    float d2 = a2.x*w4.x + a2.y*w4.y + a2.z*w4.z + a2.w*w4.w;
    float d3 = a3.x*w4.x + a3.y*w4.y + a3.z*w4.z + a3.w*w4.w;
    #pragma unroll
    for (int off = 32; off > 0; off >>= 1) {
        d0 += __shfl_down(d0, off, 64);
        d1 += __shfl_down(d1, off, 64);
        d2 += __shfl_down(d2, off, 64);
        d3 += __shfl_down(d3, off, 64);
    }
    if (lane == 0) {
        hraw[r0    ] = d0;
        hraw[r0 + 1] = d1;
        hraw[r0 + 2] = d2;
        hraw[r0 + 3] = d3;
    }
}

// Degree histograms: 4 blocks per graph, partial LDS histograms + sparse
// global-atomic merge (~0.8M atomics spread over 204800 addresses).
__global__ __launch_bounds__(256) void k_deg(const int* __restrict__ src,
                                             const int* __restrict__ dst,
                                             int* __restrict__ dego,
                                             int* __restrict__ degi) {
    __shared__ int ho[N_], hi[N_];
    const int blk = blockIdx.x, tid = threadIdx.x;
    for (int t = tid; t < N_; t += 256) { ho[t] = 0; hi[t] = 0; }
    __syncthreads();
    const int ebase = blk * (EPG_ / 4);          // 3200 edges per block
    const int nbase = (blk >> 2) * N_;           // all edges in one graph
    const int4* s4 = (const int4*)(src + ebase);
    const int4* d4 = (const int4*)(dst + ebase);
    for (int i = tid; i < EPG_ / 16; i += 256) { // 800 int4 pairs
        int4 s = s4[i]; int4 d = d4[i];
        atomicAdd(&ho[s.x - nbase], 1);
        atomicAdd(&ho[s.y - nbase], 1);
        atomicAdd(&ho[s.z - nbase], 1);
        atomicAdd(&ho[s.w - nbase], 1);
        atomicAdd(&hi[d.x - nbase], 1);
        atomicAdd(&hi[d.y - nbase], 1);
        atomicAdd(&hi[d.z - nbase], 1);
        atomicAdd(&hi[d.w - nbase], 1);
    }
    __syncthreads();
    for (int t = tid; t < N_; t += 256) {
        if (ho[t]) atomicAdd(&dego[nbase + t], ho[t]);
        if (hi[t]) atomicAdd(&degi[nbase + t], hi[t]);
    }
}

// Per-graph: normed scatter-sum -> score -> softmax partial -> bitonic top-k
// -> complement scan. Emits score, perm/pcom floats, orow (node -> output
// row), sel mask, (pm,ps). Small LDS (~11 KB).
__global__ __launch_bounds__(1024) void k_scatter(const int* __restrict__ src,
                                                  const int* __restrict__ dst,
                                                  const float* __restrict__ hraw,
                                                  const int* __restrict__ dego,
                                                  const int* __restrict__ degi,
                                                  const float* __restrict__ bp,
                                                  float* __restrict__ score,
                                                  float* __restrict__ pm,
                                                  float* __restrict__ ps,
                                                  int* __restrict__ sel,
                                                  int* __restrict__ orow,
                                                  float* __restrict__ out) {
    __shared__ float hl[N_], scl[N_];
    __shared__ float skey[512];
    __shared__ int   sidx[512], smask[N_], nscan[512];
    const int g = blockIdx.x, tid = threadIdx.x;
    const int nbase = g * N_, ebase = g * EPG_;
    const int wave = tid >> 6, lane = tid & 63;

    for (int t = tid; t < N_; t += 1024) {
        hl[t] = hraw[nbase + t] * (1.0f / sqrtf(fmaxf((float)dego[nbase + t], 1.0f)));
        scl[t] = 0.0f;
        smask[t] = 0;
    }
    __syncthreads();

    const int4* s4 = (const int4*)(src + ebase);
    const int4* d4 = (const int4*)(dst + ebase);
    for (int i = tid; i < EPG_ / 4; i += 1024) {
        int4 s = s4[i]; int4 d = d4[i];
        atomicAdd(&scl[d.x - nbase], hl[s.x - nbase]);
        atomicAdd(&scl[d.y - nbase], hl[s.y - nbase]);
        atomicAdd(&scl[d.z - nbase], hl[s.z - nbase]);
        atomicAdd(&scl[d.w - nbase], hl[s.w - nbase]);
    }
    __syncthreads();

    const float bb = bp[0];
    for (int t = tid; t < N_; t += 1024) {
        float v = scl[t] * (1.0f / sqrtf(fmaxf((float)degi[nbase + t], 1.0f))) + bb;
        scl[t] = v;
        score[nbase + t] = v;
    }
    __syncthreads();

    // Sort init (tid<512) overlapped with wave-15 softmax partial (reads scl only)
    if (tid < 512) {
        skey[tid] = (tid < N_) ? scl[tid] : NEG_INF;
        sidx[tid] = tid;
    }
    if (wave == 15) {
        float m = NEG_INF;
        for (int i = lane; i < N_; i += 64) m = fmaxf(m, scl[i]);
        #pragma unroll
        for (int o = 32; o > 0; o >>= 1) m = fmaxf(m, __shfl_xor(m, o, 64));
        float s = 0.0f;
        for (int i = lane; i < N_; i += 64) s += expf(scl[i] - m);
        #pragma unroll
        for (int o = 32; o > 0; o >>= 1) s += __shfl_xor(s, o, 64);
        if (lane == 0) { pm[g] = m; ps[g] = s; }
    }
    __syncthreads();

    // Bitonic sort, 512 wide: key = (score desc, idx asc) == jax.lax.top_k order
    for (int k = 2; k <= 512; k <<= 1) {
        for (int j = k >> 1; j > 0; j >>= 1) {
            if (tid < 512) {
                int p = tid ^ j;
                if (p > tid) {
                    float ka = skey[tid], kb = skey[p];
                    int ia = sidx[tid], ib = sidx[p];
                    bool gt_ab = (ka > kb) || (ka == kb && ia < ib);
                    bool desc = ((tid & k) == 0);
                    if (desc ? !gt_ab : gt_ab) {
                        skey[tid] = kb; skey[p] = ka;
                        sidx[tid] = ib; sidx[p] = ia;
                    }
                }
            }
            __syncthreads();
        }
    }

    if (tid < K_) {
        int id = sidx[tid];
        smask[id] = 1;
        sel[nbase + id] = 1;
        orow[nbase + id] = g * K_ + tid;               // dis rows: [0, B*K)
        out[O_PERM + g * K_ + tid] = (float)(nbase + id);
    }
    __syncthreads();
    if (tid < 512) nscan[tid] = (tid < N_) ? (1 - smask[tid]) : 0;
    __syncthreads();
    for (int off = 1; off < 512; off <<= 1) {
        int v = 0;
        if (tid < 512 && tid >= off) v = nscan[tid - off];
        __syncthreads();
        if (tid < 512) nscan[tid] += v;
        __syncthreads();
    }
    for (int t = tid; t < N_; t += 1024) {
        if (!smask[t]) {
            int pos = nscan[t] - 1;
            sel[nbase + t] = 0;
            orow[nbase + t] = B_ * K_ + g * NKC_ + pos; // com rows: [B*K, B*N)
            out[O_PCOM + g * NKC_ + pos] = (float)(nbase + t);
        }
    }
}

// Combine per-graph (max,sumexp) into global (M,S)
__global__ __launch_bounds__(256) void k_soft_comb(const float* pm, const float* ps, float* red2) {
    __shared__ float rm[256], rs[256];
    int tid = threadIdx.x;
    float m = pm[tid];
    rm[tid] = m; __syncthreads();
    for (int o = 128; o > 0; o >>= 1) { if (tid < o) rm[tid] = fmaxf(rm[tid], rm[tid + o]); __syncthreads(); }
    float M = rm[0]; __syncthreads();
    rs[tid] = ps[tid] * expf(m - M); __syncthreads();
    for (int o = 128; o > 0; o >>= 1) { if (tid < o) rs[tid] += rs[tid + o]; __syncthreads(); }
    if (tid == 0) { red2[0] = M; red2[1] = rs[0]; }
}

// Gated gather with LINEAR feature reads: wave handles 4 consecutive nodes,
// writes each row to out + orow[n]*D (dis/com contiguous). Softmax fused.
__global__ __launch_bounds__(256) void k_gather(const float* __restrict__ feat,
                                                const float* __restrict__ score,
                                                const int* __restrict__ orow,
                                                const float* __restrict__ red2,
                                                float* __restrict__ out) {
    const int gw   = (blockIdx.x * 256 + threadIdx.x) >> 6;
    const int lane = threadIdx.x & 63;
    const int n0 = gw * 4;
    const float4* fb = (const float4*)feat;
    float4 v0 = fb[(size_t)(n0    ) * 64 + lane];
    float4 v1 = fb[(size_t)(n0 + 1) * 64 + lane];
    float4 v2 = fb[(size_t)(n0 + 2) * 64 + lane];
    float4 v3 = fb[(size_t)(n0 + 3) * 64 + lane];
    float s0 = score[n0], s1 = score[n0 + 1], s2 = score[n0 + 2], s3 = score[n0 + 3];
    int   r0 = orow[n0],  r1 = orow[n0 + 1],  r2 = orow[n0 + 2],  r3 = orow[n0 + 3];
    float t0 = tanhf(s0), t1 = tanhf(s1), t2 = tanhf(s2), t3 = tanhf(s3);
    v0.x *= t0; v0.y *= t0; v0.z *= t0; v0.w *= t0;
    v1.x *= t1; v1.y *= t1; v1.z *= t1; v1.w *= t1;
    v2.x *= t2; v2.y *= t2; v2.z *= t2; v2.w *= t2;
    v3.x *= t3; v3.y *= t3; v3.z *= t3; v3.w *= t3;
    ((float4*)(out + (size_t)r0 * D_))[lane] = v0;
    ((float4*)(out + (size_t)r1 * D_))[lane] = v1;
    ((float4*)(out + (size_t)r2 * D_))[lane] = v2;
    ((float4*)(out + (size_t)r3 * D_))[lane] = v3;
    if (lane == 0) {
        float M = red2[0], S = red2[1];
        out[O_SOFT + n0    ] = expf(s0 - M) / S;
        out[O_SOFT + n0 + 1] = expf(s1 - M) / S;
        out[O_SOFT + n0 + 2] = expf(s2 - M) / S;
        out[O_SOFT + n0 + 3] = expf(s3 - M) / S;
    }
}

// Edge masks: int4 edge stream, sel (0.4 MB) is L2-resident, float4 writes.
__global__ __launch_bounds__(256) void k_mask(const int* __restrict__ src,
                                              const int* __restrict__ dst,
                                              const int* __restrict__ sel,
                                              float* __restrict__ out) {
    const int i = blockIdx.x * 256 + threadIdx.x;   // 0 .. E/4-1
    int4 s = ((const int4*)src)[i];
    int4 d = ((const int4*)dst)[i];
    int a0 = sel[s.x], a1 = sel[s.y], a2 = sel[s.z], a3 = sel[s.w];
    int b0 = sel[d.x], b1 = sel[d.y], b2 = sel[d.z], b3 = sel[d.w];
    float4 mdis, mcom;
    mdis.x = (a0 & b0) ? 1.0f : 0.0f;  mcom.x = (a0 | b0) ? 0.0f : 1.0f;
    mdis.y = (a1 & b1) ? 1.0f : 0.0f;  mcom.y = (a1 | b1) ? 0.0f : 1.0f;
    mdis.z = (a2 & b2) ? 1.0f : 0.0f;  mcom.z = (a2 | b2) ? 0.0f : 1.0f;
    mdis.w = (a3 & b3) ? 1.0f : 0.0f;  mcom.w = (a3 | b3) ? 0.0f : 1.0f;
    ((float4*)(out + O_EDIS))[i] = mdis;
    ((float4*)(out + O_ECOM))[i] = mcom;
}

extern "C" void kernel_launch(void* const* d_in, const int* in_sizes, int n_in,
                              void* d_out, int out_size, void* d_ws, size_t ws_size,
                              hipStream_t stream) {
    const float* feat = (const float*)d_in[0];
    const float* W    = (const float*)d_in[1];
    const float* bp   = (const float*)d_in[2];
    const int*   src  = (const int*)d_in[3];
    const int*   dst  = (const int*)d_in[4];
    float* out = (float*)d_out;

    char* ws = (char*)d_ws;
    int*   dego  = (int*)  (ws + 0);         // NT_ ints
    int*   degi  = (int*)  (ws + 409600);    // NT_ ints
    float* hraw  = (float*)(ws + 819200);    // NT_ floats
    float* score = (float*)(ws + 1228800);   // NT_ floats
    int*   sel   = (int*)  (ws + 1638400);   // NT_ ints
    int*   orow  = (int*)  (ws + 2048000);   // NT_ ints
    float* pm    = (float*)(ws + 2457600);   // B_ floats
    float* ps    = (float*)(ws + 2458624);   // B_ floats
    float* red2  = (float*)(ws + 2459648);   // 2 floats

    hipMemsetAsync(ws, 0, 2 * NT_ * sizeof(int), stream);   // zero dego/degi

    k_h        <<<NT_ / 16 / 64, 256, 0, stream>>>(feat, W, hraw);          // 6400 blocks
    k_deg      <<<1024,          256, 0, stream>>>(src, dst, dego, degi);
    k_scatter  <<<B_,           1024, 0, stream>>>(src, dst, hraw, dego, degi, bp,
                                                   score, pm, ps, sel, orow, out);
    k_soft_comb<<<1,             256, 0, stream>>>(pm, ps, red2);
    k_gather   <<<NT_ / 16 / 64, 256, 0, stream>>>(feat, score, orow, red2, out); // 6400 blocks
    k_mask     <<<E_ / 4 / 256,  256, 0, stream>>>(src, dst, sel, out);     // 3200 blocks
}